// Round 7
// baseline (152.879 us; speedup 1.0000x reference)
//
#include <hip/hip_runtime.h>

#define BS 32
#define NA 512
#define ID 128
#define NH 8
#define HD 64
#define NHD 512   // NH*HD
#define NEG 0.2f
#define NC 32     // scalar chunk count (G=16) for zps/znp
#define CH 16
#define NCH 8     // 64-row vector chunks per bh
#define BPAD 136  // B LDS col stride (bf16 elems): 272B -> 2-way bank alias (free)

typedef short bf16x8 __attribute__((ext_vector_type(8)));
typedef float f32x4 __attribute__((ext_vector_type(4)));

__device__ inline unsigned f2bf_bits(float x) {   // RNE f32 -> bf16 bits
  unsigned u = __float_as_uint(x);
  return (u + 0x7FFFu + ((u >> 16) & 1u)) >> 16;
}

__device__ inline void split8(const float4& x, const float4& y,
                              bf16x8& hi, bf16x8& lo) {
  float f[8] = {x.x, x.y, x.z, x.w, y.x, y.y, y.z, y.w};
  #pragma unroll
  for (int j = 0; j < 8; ++j) {
    unsigned hb = f2bf_bits(f[j]);
    float r = f[j] - __uint_as_float(hb << 16);
    unsigned lb = f2bf_bits(r);
    hi[j] = (short)hb;
    lo[j] = (short)lb;
  }
}

// K1 (MFMA): hp = h @ W via split-bf16 3-pass, fp32 accumulate (verified R4)
// + s/t epilogue: block holds the full 64-col head slice of its 128 rows in
// acc, so s = hp·a_src / t = hp·a_dst falls out of a 4-FMA partial + 16-lane
// shfl tree (R0-proven reduction). Writes hp, s, t to d_ws.
__global__ __launch_bounds__(256, 4) void k1_mfma(
    const float* __restrict__ h, const float* __restrict__ W,
    const float* __restrict__ att, float* __restrict__ hp,
    float* __restrict__ sG, float* __restrict__ tG) {
  __shared__ unsigned short Bhi[64 * BPAD];
  __shared__ unsigned short Blo[64 * BPAD];

  int blk = blockIdx.x;
  int mt = blk >> 3;            // M-tile 0..127 (128 rows each)
  int n0 = (blk & 7) * 64;      // N-tile start col
  int m0 = mt * 128;
  int b = mt >> 2;              // batch
  int nbase = (mt & 3) * 128;   // agent-row base within batch
  int head = n0 >> 6;
  int t = threadIdx.x;
  int lane = t & 63, w = t >> 6;
  int q = lane >> 4, ml = lane & 15;

  // ---- stage W[n0..n0+63] split+transposed into LDS ----
  {
    int c = t & 63, kq = t >> 6;
    const float* wsrc = W + (size_t)kq * 32 * NHD + n0 + c;
    #pragma unroll 4
    for (int kk = 0; kk < 32; ++kk) {
      int k = kq * 32 + kk;
      float x = wsrc[(size_t)kk * NHD];
      unsigned hb = f2bf_bits(x);
      float r = x - __uint_as_float(hb << 16);
      Bhi[c * BPAD + k] = (unsigned short)hb;
      Blo[c * BPAD + k] = (unsigned short)f2bf_bits(r);
    }
  }
  __syncthreads();

  f32x4 acc[2][4];
  #pragma unroll
  for (int mf = 0; mf < 2; ++mf)
    #pragma unroll
    for (int nf = 0; nf < 4; ++nf)
      acc[mf][nf] = (f32x4){0.f, 0.f, 0.f, 0.f};

  const float* A0 = h + (size_t)(m0 + w * 32 + ml) * ID;

  #pragma unroll
  for (int ks = 0; ks < 4; ++ks) {
    int ko = ks * 32 + q * 8;          // my k mapping: k = 8*quarter + elem
    bf16x8 ah[2], al[2];
    #pragma unroll
    for (int mf = 0; mf < 2; ++mf) {
      const float* ap = A0 + mf * 16 * ID + ko;
      float4 f0 = *(const float4*)ap;
      float4 f1 = *(const float4*)(ap + 4);
      split8(f0, f1, ah[mf], al[mf]);
    }
    #pragma unroll
    for (int nf = 0; nf < 4; ++nf) {
      int bo = (nf * 16 + ml) * BPAD + ko;   // same k mapping on B side
      bf16x8 bh = *(const bf16x8*)&Bhi[bo];
      bf16x8 bl = *(const bf16x8*)&Blo[bo];
      #pragma unroll
      for (int mf = 0; mf < 2; ++mf) {
        acc[mf][nf] = __builtin_amdgcn_mfma_f32_16x16x32_bf16(ah[mf], bh, acc[mf][nf], 0, 0, 0);
        acc[mf][nf] = __builtin_amdgcn_mfma_f32_16x16x32_bf16(ah[mf], bl, acc[mf][nf], 0, 0, 0);
        acc[mf][nf] = __builtin_amdgcn_mfma_f32_16x16x32_bf16(al[mf], bh, acc[mf][nf], 0, 0, 0);
      }
    }
  }

  // ---- hp store: D layout col=lane&15, row=4*(lane>>4)+reg (HW-verified) ----
  {
    float* ob = hp + (((size_t)b * NH + head) * NA + nbase + w * 32) * HD + ml;
    #pragma unroll
    for (int mf = 0; mf < 2; ++mf)
      #pragma unroll
      for (int nf = 0; nf < 4; ++nf)
        #pragma unroll
        for (int r = 0; r < 4; ++r)
          ob[(size_t)(mf * 16 + q * 4 + r) * HD + nf * 16] = acc[mf][nf][r];
  }

  // ---- s/t epilogue: per-row dot with a_src/a_dst + 16-lane tree reduce ----
  {
    float a_s[4], a_d[4];
    #pragma unroll
    for (int nf = 0; nf < 4; ++nf) {
      a_s[nf] = att[head * 128 + nf * 16 + ml];
      a_d[nf] = att[head * 128 + 64 + nf * 16 + ml];
    }
    #pragma unroll
    for (int mf = 0; mf < 2; ++mf) {
      #pragma unroll
      for (int r = 0; r < 4; ++r) {
        float sp = 0.f, tp = 0.f;
        #pragma unroll
        for (int nf = 0; nf < 4; ++nf) {
          float c = acc[mf][nf][r];
          sp += c * a_s[nf]; tp += c * a_d[nf];
        }
        #pragma unroll
        for (int m = 1; m < 16; m <<= 1) {
          sp += __shfl_xor(sp, m, 64);
          tp += __shfl_xor(tp, m, 64);
        }
        if (ml == 0) {
          int row = nbase + w * 32 + mf * 16 + q * 4 + r;
          size_t o = ((size_t)b * NH + head) * NA + row;
          sG[o] = sp; tG[o] = tp;
        }
      }
    }
  }
}

// K2a: per (b,h): dual sort + scalar tables + per-rank info. NO V access —
// reads only s,t (2KB/block). Writes tpm/wp/wn (sorted order), abi, Earr.
__global__ __launch_bounds__(512, 2) void k2a_sort(
    const float* __restrict__ sG, const float* __restrict__ tG,
    int* __restrict__ tpmG, float* __restrict__ wpG, float* __restrict__ wnG,
    float4* __restrict__ abiG, int* __restrict__ EarrG) {
  __shared__ float tv[NA]; __shared__ int tpm[NA];
  __shared__ float sv[NA]; __shared__ int spm[NA];
  __shared__ float wp[NA]; __shared__ float wn[NA];
  __shared__ float zps[NA + 1]; __shared__ float znp[NA + 1];
  __shared__ float szP[NC]; __shared__ float szN[NC];
  __shared__ float sufZ[NC + 1]; __shared__ float preZ[NC + 1];
  __shared__ int jsr[NA];

  int bh = blockIdx.x;
  int t = threadIdx.x;

  float vt = tG[(size_t)bh * NA + t]; int it = t;
  float vs = sG[(size_t)bh * NA + t]; int is_ = t;

  // ---- dual hybrid bitonic sort (t asc, s asc), value+index in regs ----
  for (int size = 2; size <= NA; size <<= 1) {
    bool dirAsc = ((t & size) == 0);
    for (int stride = size >> 1; stride > 0; stride >>= 1) {
      float pt, ps; int pit, pis;
      if (stride >= 64) {
        tv[t] = vt; tpm[t] = it; sv[t] = vs; spm[t] = is_;
        __syncthreads();
        pt = tv[t ^ stride]; pit = tpm[t ^ stride];
        ps = sv[t ^ stride]; pis = spm[t ^ stride];
        __syncthreads();
      } else {
        pt = __shfl_xor(vt, stride, 64); pit = __shfl_xor(it, stride, 64);
        ps = __shfl_xor(vs, stride, 64); pis = __shfl_xor(is_, stride, 64);
      }
      bool mn = (((t & stride) == 0) == dirAsc);
      if (mn ? (pt < vt) : (pt > vt)) { vt = pt; it = pit; }
      if (mn ? (ps < vs) : (ps > vs)) { vs = ps; is_ = pis; }
    }
  }
  tv[t] = vt; tpm[t] = it; sv[t] = vs; spm[t] = is_;
  __syncthreads();

  float cmax = fmaxf(tv[NA - 1], 0.f);
  float amax = fmaxf(sv[NA - 1], 0.f);
  float wpt = __expf(vt - cmax);
  float wnt = __expf(NEG * vt - cmax);
  wp[t] = wpt; wn[t] = wnt;
  tpmG[(size_t)bh * NA + t] = it;
  wpG[(size_t)bh * NA + t] = wpt;
  wnG[(size_t)bh * NA + t] = wnt;
  __syncthreads();

  // ---- scalar chunk sums (G=16) ----
  if (t < NC) {
    int c = t; float a = 0.f;
    for (int j = c * CH; j < c * CH + CH; ++j) a += wp[j];
    szP[c] = a;
  } else if (t < 2 * NC) {
    int c = t - NC; float a = 0.f;
    for (int j = c * CH; j < c * CH + CH; ++j) a += wn[j];
    szN[c] = a;
  }
  __syncthreads();

  if (t == 0) {
    float run = 0.f; sufZ[NC] = 0.f;
    for (int cc = NC - 1; cc >= 0; --cc) { run += szP[cc]; sufZ[cc] = run; }
  } else if (t == 1) {
    float run = 0.f;
    for (int cc = 0; cc <= NC; ++cc) { preZ[cc] = run; if (cc < NC) run += szN[cc]; }
  }
  __syncthreads();

  // ---- full-resolution scalar denominator tables + per-rank js ----
  int myjs;
  {
    int ch = t >> 4;
    float a = 0.f;
    for (int k = t; k < ch * CH + CH; ++k) a += wp[k];
    zps[t] = a + sufZ[ch + 1];
    float b2 = 0.f;
    for (int k = ch * CH; k < t; ++k) b2 += wn[k];
    znp[t] = preZ[ch] + b2;
    if (t == 0) { zps[NA] = 0.f; znp[NA] = preZ[NC]; }
    float key = -vs;
    int lo = 0, hi = NA;
    while (lo < hi) { int mid = (lo + hi) >> 1; if (tv[mid] < key) lo = mid + 1; else hi = mid; }
    jsr[t] = lo; myjs = lo;
  }
  __syncthreads();

  // ---- abi + Earr ----
  {
    float A = __expf(vs - amax);
    float B = __expf(NEG * vs - amax);
    float den = A * zps[myjs] + B * znp[myjs];
    float4 qv; qv.x = A; qv.y = B; qv.z = 1.f / den; qv.w = __int_as_float(is_);
    abiG[(size_t)bh * NA + t] = qv;
    int lo = 0, hi = NA;
    while (lo < hi) { int mid = (lo + hi) >> 1; if (jsr[mid] > t) lo = mid + 1; else hi = mid; }
    EarrG[(size_t)bh * NA + t] = lo;
  }
}

// K2b: per (bh, chunk) wave: chunk vector sums. 2048 blocks -> 8 waves/CU,
// no barriers after the LDS stage: gather latency hidden by TLP.
__global__ __launch_bounds__(64) void k2b_sums(
    const float* __restrict__ hp, const int* __restrict__ tpmG,
    const float* __restrict__ wpG, const float* __restrict__ wnG,
    float* __restrict__ rawPG, float* __restrict__ rawNG) {
  __shared__ float wpS[64], wnS[64]; __shared__ int tpS[64];
  int blk = blockIdx.x;
  int bh = blk >> 3, c = blk & 7;
  int lane = threadIdx.x;
  size_t base = (size_t)bh * NA + c * 64;
  wpS[lane] = wpG[base + lane];
  wnS[lane] = wnG[base + lane];
  tpS[lane] = tpmG[base + lane];
  __syncthreads();
  const float* vb = hp + (size_t)bh * NA * HD;
  float aP = 0.f, aN = 0.f;
  #pragma unroll 4
  for (int jj = 0; jj < 64; ++jj) {
    float vv = vb[(size_t)tpS[jj] * HD + lane];
    aP += wpS[jj] * vv;
    aN += wnS[jj] * vv;
  }
  rawPG[base + lane] = aP;   // layout [bh][c][lane]
  rawNG[base + lane] = aN;
}

// K2d: per (bh, chunk) wave: seeds via 8-term scan of chunk sums (same
// summation order as R4 -> bitwise-identical), then the verified 64-step
// sweep with inline emission. 2048 independent waves, no barriers in sweep.
__global__ __launch_bounds__(64) void k2d_apply(
    const float* __restrict__ hp, const int* __restrict__ tpmG,
    const float* __restrict__ wpG, const float* __restrict__ wnG,
    const int* __restrict__ EarrG, const float4* __restrict__ abiG,
    const float* __restrict__ rawPG, const float* __restrict__ rawNG,
    float* __restrict__ out) {
  __shared__ float wpS[64], wnS[64]; __shared__ int tpS[64]; __shared__ int eS[64];
  int blk = blockIdx.x;
  int bh = blk >> 3, c = blk & 7;
  int lane = threadIdx.x;
  size_t base = (size_t)bh * NA + c * 64;
  wpS[lane] = wpG[base + lane];
  wnS[lane] = wnG[base + lane];
  tpS[lane] = tpmG[base + lane];
  eS[lane]  = EarrG[base + lane];
  int eprev = (c == 0) ? NA : EarrG[base - 1];   // wave-uniform broadcast
  // seeds (match R4's scan order exactly)
  size_t rb = (size_t)bh * NA + lane;
  float sufPv = 0.f;
  for (int cc = NCH - 1; cc >= c; --cc) sufPv += rawPG[rb + cc * 64];
  float preSeedN = 0.f;
  for (int cc = 0; cc < c; ++cc) preSeedN += rawNG[rb + cc * 64];
  __syncthreads();

  const float* vb = hp + (size_t)bh * NA * HD;
  const float4* ab = abiG + (size_t)bh * NA;
  float runN = 0.f;
  size_t obase = (size_t)bh * NA * HD + lane;
  #pragma unroll 2
  for (int jj = 0; jj < 64; ++jj) {
    float vv = vb[(size_t)tpS[jj] * HD + lane];
    int ecur = eS[jj];
    float preNv = preSeedN + runN;
    for (int r = ecur; r < eprev; ++r) {   // ranks with js == 64c+jj
      float4 qv = ab[r];
      float x = (qv.x * sufPv + qv.y * preNv) * qv.z;
      int orow = __float_as_int(qv.w);
      out[obase + (size_t)orow * HD] = x > 0.f ? x : __expf(x) - 1.f;
    }
    sufPv -= wpS[jj] * vv;
    runN  += wnS[jj] * vv;
    eprev = ecur;
  }
  if (c == NCH - 1) {                      // group js == 512: ranks [0, E[511])
    float preNv = preSeedN + runN;         // == total N prefix
    for (int r = 0; r < eprev; ++r) {
      float4 qv = ab[r];
      float x = (qv.y * preNv) * qv.z;     // sufP[512] == 0
      int orow = __float_as_int(qv.w);
      out[obase + (size_t)orow * HD] = x > 0.f ? x : __expf(x) - 1.f;
    }
  }
}

extern "C" void kernel_launch(void* const* d_in, const int* in_sizes, int n_in,
                              void* d_out, int out_size, void* d_ws, size_t ws_size,
                              hipStream_t stream) {
  const float* h   = (const float*)d_in[0];
  const float* W   = (const float*)d_in[1];
  const float* att = (const float*)d_in[2];
  float* out = (float*)d_out;

  const size_t R = (size_t)BS * NH * NA;        // 131072 rows total
  float* hp    = (float*)d_ws;                  // 33.5 MB
  float* sG    = hp + (size_t)BS * NH * NA * HD;
  float* tG    = sG + R;
  float* wpG   = tG + R;
  float* wnG   = wpG + R;
  int*   tpmG  = (int*)(wnG + R);
  float4* abiG = (float4*)(tpmG + R);           // 16B-aligned (offset %4==0 floats)
  int*   EarrG = (int*)(abiG + R);
  float* rawPG = (float*)(EarrG + R);
  float* rawNG = rawPG + R;

  k1_mfma <<<dim3(1024),       dim3(256), 0, stream>>>(h, W, att, hp, sG, tG);
  k2a_sort<<<dim3(BS * NH),    dim3(512), 0, stream>>>(sG, tG, tpmG, wpG, wnG, abiG, EarrG);
  k2b_sums<<<dim3(BS * NH * 8), dim3(64), 0, stream>>>(hp, tpmG, wpG, wnG, rawPG, rawNG);
  k2d_apply<<<dim3(BS * NH * 8), dim3(64), 0, stream>>>(hp, tpmG, wpG, wnG, EarrG, abiG,
                                                        rawPG, rawNG, out);
}

// Round 8
// 137.026 us; speedup vs baseline: 1.1157x; 1.1157x over previous
//
#include <hip/hip_runtime.h>

#define BS 32
#define NA 512
#define ID 128
#define NH 8
#define HD 64
#define NHD 512   // NH*HD
#define NEG 0.2f
#define NC 32     // scalar chunk count (G=16) for zps/znp
#define CH 16
#define NW 8      // waves per k2 block (512 threads)
#define BPAD 136  // B LDS col stride (bf16 elems): 272B -> 2-way bank alias (free)

typedef short bf16x8 __attribute__((ext_vector_type(8)));
typedef float f32x4 __attribute__((ext_vector_type(4)));

__device__ inline unsigned f2bf_bits(float x) {   // RNE f32 -> bf16 bits
  unsigned u = __float_as_uint(x);
  return (u + 0x7FFFu + ((u >> 16) & 1u)) >> 16;
}

// split 8 floats into bf16 hi + bf16 lo fragments (static indices only)
__device__ inline void split8(const float4& x, const float4& y,
                              bf16x8& hi, bf16x8& lo) {
  float f[8] = {x.x, x.y, x.z, x.w, y.x, y.y, y.z, y.w};
  #pragma unroll
  for (int j = 0; j < 8; ++j) {
    unsigned hb = f2bf_bits(f[j]);
    float r = f[j] - __uint_as_float(hb << 16);
    unsigned lb = f2bf_bits(r);
    hi[j] = (short)hb;
    lo[j] = (short)lb;
  }
}

// K1 (MFMA): hp = h @ W via split-bf16 3-pass (hi*hi + hi*lo + lo*hi), fp32
// accumulate. Byte-identical to R4 (verified best). Writes into io (d_out).
__global__ __launch_bounds__(256, 4) void k1_mfma(
    const float* __restrict__ h, const float* __restrict__ W,
    float* __restrict__ io) {
  __shared__ unsigned short Bhi[64 * BPAD];
  __shared__ unsigned short Blo[64 * BPAD];

  int blk = blockIdx.x;
  int mt = blk >> 3;            // M-tile 0..127 (128 rows each)
  int n0 = (blk & 7) * 64;      // N-tile start col
  int m0 = mt * 128;
  int b = mt >> 2;              // batch
  int nbase = (mt & 3) * 128;   // agent-row base within batch
  int head = n0 >> 6;
  int t = threadIdx.x;
  int lane = t & 63, w = t >> 6;
  int q = lane >> 4, ml = lane & 15;

  // ---- stage W[n0..n0+63] split+transposed into LDS ----
  {
    int c = t & 63, kq = t >> 6;
    const float* wsrc = W + (size_t)kq * 32 * NHD + n0 + c;
    #pragma unroll 4
    for (int kk = 0; kk < 32; ++kk) {
      int k = kq * 32 + kk;
      float x = wsrc[(size_t)kk * NHD];
      unsigned hb = f2bf_bits(x);
      float r = x - __uint_as_float(hb << 16);
      Bhi[c * BPAD + k] = (unsigned short)hb;
      Blo[c * BPAD + k] = (unsigned short)f2bf_bits(r);
    }
  }
  __syncthreads();

  f32x4 acc[2][4];
  #pragma unroll
  for (int mf = 0; mf < 2; ++mf)
    #pragma unroll
    for (int nf = 0; nf < 4; ++nf)
      acc[mf][nf] = (f32x4){0.f, 0.f, 0.f, 0.f};

  const float* A0 = h + (size_t)(m0 + w * 32 + ml) * ID;

  #pragma unroll
  for (int ks = 0; ks < 4; ++ks) {
    int ko = ks * 32 + q * 8;          // my k mapping: k = 8*quarter + elem
    bf16x8 ah[2], al[2];
    #pragma unroll
    for (int mf = 0; mf < 2; ++mf) {
      const float* ap = A0 + mf * 16 * ID + ko;
      float4 f0 = *(const float4*)ap;
      float4 f1 = *(const float4*)(ap + 4);
      split8(f0, f1, ah[mf], al[mf]);
    }
    #pragma unroll
    for (int nf = 0; nf < 4; ++nf) {
      int bo = (nf * 16 + ml) * BPAD + ko;   // same k mapping on B side
      bf16x8 bh = *(const bf16x8*)&Bhi[bo];
      bf16x8 bl = *(const bf16x8*)&Blo[bo];
      #pragma unroll
      for (int mf = 0; mf < 2; ++mf) {
        acc[mf][nf] = __builtin_amdgcn_mfma_f32_16x16x32_bf16(ah[mf], bh, acc[mf][nf], 0, 0, 0);
        acc[mf][nf] = __builtin_amdgcn_mfma_f32_16x16x32_bf16(ah[mf], bl, acc[mf][nf], 0, 0, 0);
        acc[mf][nf] = __builtin_amdgcn_mfma_f32_16x16x32_bf16(al[mf], bh, acc[mf][nf], 0, 0, 0);
      }
    }
  }

  // ---- epilogue: D layout col=lane&15, row=4*(lane>>4)+reg (HW-verified) ----
  {
    float* ob = io + (((size_t)b * NH + head) * NA + nbase + w * 32) * HD + ml;
    #pragma unroll
    for (int mf = 0; mf < 2; ++mf)
      #pragma unroll
      for (int nf = 0; nf < 4; ++nf)
        #pragma unroll
        for (int r = 0; r < 4; ++r)
          ob[(size_t)(mf * 16 + q * 4 + r) * HD + nf * 16] = acc[mf][nf][r];
  }
}

// K2 (in-place, V staged in LDS): io holds hp on entry, final output on exit.
// Same math as R4 bitwise; the scratch-spilled vreg[64] (VGPR_Count=56 proved
// local-memory placement) is replaced by VS[512][64] in LDS: phase A gathers
// each sorted V row from global ONCE and deposits it at VS[j][lane]
// (stride-1, conflict-free); the sweep reads LDS. Metadata shrunk to fit
// 160 KiB: u16 index arrays, abi dropped (A/B/den recomputed inline at
// emission — R2-verified), raw seed arrays folded into in-place scans.
__global__ __launch_bounds__(512) void k2_fused(
    const float* __restrict__ att, float* __restrict__ io) {
  __shared__ float VS[NA * 64];                      // 128 KiB, sorted order
  __shared__ float tv[NA]; __shared__ float sv[NA];
  __shared__ unsigned short tpm[NA]; __shared__ unsigned short spm[NA];
  __shared__ float wp[NA]; __shared__ float wn[NA];
  __shared__ float sufPc[(NW + 1) * 64]; __shared__ float preNc[(NW + 1) * 64];
  __shared__ float zps[NA + 1]; __shared__ float znp[NA + 1];
  __shared__ float szP[NC]; __shared__ float szN[NC];
  __shared__ float sufZ[NC + 1]; __shared__ float preZ[NC + 1];
  __shared__ unsigned short jsr[NA]; __shared__ unsigned short Earr[NA];
  __shared__ float asrc[HD]; __shared__ float adst[HD];

  int bh = blockIdx.x;
  int head = bh & (NH - 1);
  int t = threadIdx.x;
  int lane = t & 63, w = t >> 6;
  float* vbase = io + (size_t)bh * NA * HD;

  if (t < 2 * HD) {
    float a = att[head * 2 * HD + t];
    if (t < HD) asrc[t] = a; else adst[t - HD] = a;
  }
  __syncthreads();

  // ---- s,t row-dots: thread t = natural row t (float4 loads, L3-hot) ----
  float vt, vs; int it = t, is_ = t;
  {
    const float4* vr = (const float4*)(vbase + (size_t)t * HD);
    float s0 = 0.f, s1 = 0.f, t0 = 0.f, t1 = 0.f;
    #pragma unroll
    for (int j = 0; j < HD / 4; j += 2) {
      float4 v0 = vr[j], v1 = vr[j + 1];
      s0 += v0.x*asrc[4*j+0] + v0.y*asrc[4*j+1] + v0.z*asrc[4*j+2] + v0.w*asrc[4*j+3];
      t0 += v0.x*adst[4*j+0] + v0.y*adst[4*j+1] + v0.z*adst[4*j+2] + v0.w*adst[4*j+3];
      s1 += v1.x*asrc[4*j+4] + v1.y*asrc[4*j+5] + v1.z*asrc[4*j+6] + v1.w*asrc[4*j+7];
      t1 += v1.x*adst[4*j+4] + v1.y*adst[4*j+5] + v1.z*adst[4*j+6] + v1.w*adst[4*j+7];
    }
    vs = s0 + s1; vt = t0 + t1;
  }

  // ---- dual hybrid bitonic sort (t asc, s asc), value+index in regs ----
  for (int size = 2; size <= NA; size <<= 1) {
    bool dirAsc = ((t & size) == 0);
    for (int stride = size >> 1; stride > 0; stride >>= 1) {
      float pt, ps; int pit, pis;
      if (stride >= 64) {
        tv[t] = vt; tpm[t] = (unsigned short)it;
        sv[t] = vs; spm[t] = (unsigned short)is_;
        __syncthreads();
        pt = tv[t ^ stride]; pit = (int)tpm[t ^ stride];
        ps = sv[t ^ stride]; pis = (int)spm[t ^ stride];
        __syncthreads();
      } else {
        pt = __shfl_xor(vt, stride, 64); pit = __shfl_xor(it, stride, 64);
        ps = __shfl_xor(vs, stride, 64); pis = __shfl_xor(is_, stride, 64);
      }
      bool mn = (((t & stride) == 0) == dirAsc);
      if (mn ? (pt < vt) : (pt > vt)) { vt = pt; it = pit; }
      if (mn ? (ps < vs) : (ps > vs)) { vs = ps; is_ = pis; }
    }
  }
  tv[t] = vt; tpm[t] = (unsigned short)it;
  sv[t] = vs; spm[t] = (unsigned short)is_;
  __syncthreads();

  float cmax = fmaxf(tv[NA - 1], 0.f);
  float amax = fmaxf(sv[NA - 1], 0.f);
  wp[t] = __expf(vt - cmax);
  wn[t] = __expf(NEG * vt - cmax);
  __syncthreads();

  // ---- phase A: gather sorted V rows ONCE -> LDS + raw weighted seeds ----
  {
    float aP = 0.f, aN = 0.f;
    #pragma unroll 4
    for (int jj = 0; jj < 64; ++jj) {
      int j = (w << 6) + jj;
      float vv = vbase[(size_t)tpm[j] * HD + lane];
      VS[j * 64 + lane] = vv;
      aP += wp[j] * vv;
      aN += wn[j] * vv;
    }
    sufPc[w * 64 + lane] = aP;   // raw; converted in place below
    preNc[w * 64 + lane] = aN;
  }
  __syncthreads();

  // ---- in-place cross-wave scans + scalar chunk sums ----
  if (t < 64) {
    float run = 0.f;
    sufPc[NW * 64 + t] = 0.f;
    for (int ww = NW - 1; ww >= 0; --ww) {
      run += sufPc[ww * 64 + t];
      sufPc[ww * 64 + t] = run;
    }
  } else if (t < 128) {
    int d = t - 64; float run = 0.f;
    for (int ww = 0; ww < NW; ++ww) {
      float raw = preNc[ww * 64 + d];
      preNc[ww * 64 + d] = run;
      run += raw;
    }
    preNc[NW * 64 + d] = run;
  } else if (t < 160) {
    int c = t - 128; float a = 0.f;
    for (int j = c * CH; j < c * CH + CH; ++j) a += wp[j];
    szP[c] = a;
  } else if (t < 192) {
    int c = t - 160; float a = 0.f;
    for (int j = c * CH; j < c * CH + CH; ++j) a += wn[j];
    szN[c] = a;
  }
  __syncthreads();

  if (t == 0) {
    float run = 0.f; sufZ[NC] = 0.f;
    for (int cc = NC - 1; cc >= 0; --cc) { run += szP[cc]; sufZ[cc] = run; }
  } else if (t == 1) {
    float run = 0.f;
    for (int cc = 0; cc <= NC; ++cc) { preZ[cc] = run; if (cc < NC) run += szN[cc]; }
  }
  __syncthreads();

  // ---- full-resolution scalar denominator tables + per-rank js ----
  {
    int ch = t >> 4;
    float a = 0.f;
    for (int k = t; k < ch * CH + CH; ++k) a += wp[k];
    zps[t] = a + sufZ[ch + 1];
    float b2 = 0.f;
    for (int k = ch * CH; k < t; ++k) b2 += wn[k];
    znp[t] = preZ[ch] + b2;
    if (t == 0) { zps[NA] = 0.f; znp[NA] = preZ[NC]; }
    // js for s-rank t (vs in reg): first sorted-t position with tv >= -vs
    float key = -vs;
    int lo = 0, hi = NA;
    while (lo < hi) { int mid = (lo + hi) >> 1; if (tv[mid] < key) lo = mid + 1; else hi = mid; }
    jsr[t] = (unsigned short)lo;
  }
  __syncthreads();

  // ---- E[j]: first rank with jsr <= j (jsr sorted descending) ----
  {
    int lo = 0, hi = NA;
    while (lo < hi) { int mid = (lo + hi) >> 1; if ((int)jsr[mid] > t) lo = mid + 1; else hi = mid; }
    Earr[t] = (unsigned short)lo;
  }
  __syncthreads();

  // ---- ascending sweep: V from LDS, inline A/B/den recompute at emission ----
  {
    float sufPv = sufPc[w * 64 + lane];      // suffix incl. this wave's rows
    float preSeedN = preNc[w * 64 + lane];   // exact prefix before this wave
    float runN = 0.f;
    size_t obase = (size_t)bh * NA * HD + lane;
    int jb = w << 6;
    int eprev = (w == 0) ? NA : (int)Earr[jb - 1];   // E[j-1] carried
    #pragma unroll 1
    for (int jj = 0; jj < 64; ++jj) {
      int j = jb + jj;
      float vv = VS[j * 64 + lane];
      int ecur = (int)Earr[j];
      float preNv = preSeedN + runN;
      for (int r = ecur; r < eprev; ++r) {   // ranks with js == j
        float s = sv[r];
        float A = __expf(s - amax);
        float B = __expf(NEG * s - amax);
        float inv = 1.f / (A * zps[j] + B * znp[j]);
        float x = (A * sufPv + B * preNv) * inv;
        int orow = (int)spm[r];
        io[obase + (size_t)orow * HD] = x > 0.f ? x : __expf(x) - 1.f;
      }
      sufPv -= wp[j] * vv;
      runN  += wn[j] * vv;
      eprev = ecur;
    }
    if (w == NW - 1) {                       // group js == 512: [0, E[511])
      float preNv = preSeedN + runN;         // == total N prefix
      for (int r = 0; r < eprev; ++r) {
        float s = sv[r];
        float A = __expf(s - amax);
        float B = __expf(NEG * s - amax);
        float inv = 1.f / (A * zps[NA] + B * znp[NA]);  // zps[NA]==0
        float x = (B * preNv) * inv;
        int orow = (int)spm[r];
        io[obase + (size_t)orow * HD] = x > 0.f ? x : __expf(x) - 1.f;
      }
    }
  }
}

extern "C" void kernel_launch(void* const* d_in, const int* in_sizes, int n_in,
                              void* d_out, int out_size, void* d_ws, size_t ws_size,
                              hipStream_t stream) {
  const float* h   = (const float*)d_in[0];
  const float* W   = (const float*)d_in[1];
  const float* att = (const float*)d_in[2];
  float* io = (float*)d_out;
  (void)d_ws; (void)ws_size;

  k1_mfma <<<dim3(1024),    dim3(256), 0, stream>>>(h, W, io);
  k2_fused<<<dim3(BS * NH), dim3(512), 0, stream>>>(att, io);
}